// Round 17
// baseline (103.284 us; speedup 1.0000x reference)
//
#include <hip/hip_runtime.h>

#define EPS 1e-5f

static constexpr int D  = 128;
static constexpr int L  = 256;
static constexpr int C  = 256;
static constexpr int OC = 32;
static constexpr int PC = 256;

typedef __attribute__((ext_vector_type(8))) short bfrag8;   // 8 bf16 (4 VGPR)
typedef __attribute__((ext_vector_type(4))) short bhalf4;   // 4 bf16 (8B)
typedef __attribute__((ext_vector_type(4))) float f32x4;
typedef __attribute__((ext_vector_type(4))) unsigned int u32x4;

__device__ inline unsigned short f2bf(float f) {
  union { float f; unsigned u; } v; v.f = f;
  unsigned r = v.u + 0x7FFF + ((v.u >> 16) & 1);   // RNE
  return (unsigned short)(r >> 16);
}

// ---------------- Kernel 1: prep (blocks 0..63) + LayerNorm/projection (blocks 64..575) ----
// prep part: Wbf3 = Wout bf16 in MFMA A-frag order (M-side = p), k''-ordered:
//   k'' = q*32 + c2*8 + hi*4 + r  <->  cc = hi*16 + c2*4 + r; orig = cc*32 + q.
//   elem ((pf*32+ks)*64+lane)*8+jj = Wout[p = pf*16+(lane&15)][orig(k'')],
//   k'' = ks*32 + (lane>>4)*8 + jj.
// ln part: block = 8 d x 8 l rows; weight frags built inline from Wl/Wr (L2-hot).
__global__ __launch_bounds__(256, 4)
void prep_ln(const float* __restrict__ msa,
             const float* __restrict__ lnw, const float* __restrict__ lnb,
             const float* __restrict__ Wl, const float* __restrict__ Wr,
             const float* __restrict__ Wout,
             const float* __restrict__ bl, const float* __restrict__ br,
             unsigned short* __restrict__ Wbf3,
             unsigned short* __restrict__ leftT, unsigned short* __restrict__ rightT) {
  const int t = threadIdx.x;
  const int b = blockIdx.x;

  if (b < 64) {   // ---- Wbf3 frag-pack: 64 blocks x 256 thr x 16 elems ----
    #pragma unroll
    for (int j2 = 0; j2 < 4; ++j2) {
      const int e0 = (b * 256 + t) * 16 + j2 * 4;
      const int lane = (e0 >> 3) & 63, ks = (e0 >> 9) & 31, pf = e0 >> 14;
      const int p = pf * 16 + (lane & 15);
      unsigned short v[4];
      #pragma unroll
      for (int j = 0; j < 4; ++j) {
        const int kp = ks * 32 + ((lane >> 4) * 8) + ((e0 + j) & 7);   // k''
        const int q = kp >> 5, t5 = kp & 31;
        const int cc = ((t5 >> 2) & 1) * 16 + (t5 >> 3) * 4 + (t5 & 3);
        v[j] = f2bf(Wout[p * 1024 + cc * 32 + q]);
      }
      *(bhalf4*)(Wbf3 + e0) = *(bhalf4*)v;
    }
    return;
  }

  // ---- ln_proj part ----
  __shared__ char xb[32768];   // [64 r][256 c] bf16, swizzled ^((r&7)<<4)

  const int bb = b - 64;
  const int lane = t & 63, w = t >> 6;
  const int d0 = (bb & 15) * 8, l0 = (bb >> 4) * 8;

  float4 xv[16];
  #pragma unroll
  for (int i = 0; i < 16; ++i) {
    const int r = i * 4 + w, dd = r & 7, ll = r >> 3;
    xv[i] = *(const float4*)(msa + ((size_t)(d0 + dd) * 256 + (l0 + ll)) * 256 + lane * 4);
  }

  // build weight frags inline: n = w*16+(lane&15)
  bfrag8 wf[8];
  {
    const int n = w * 16 + (lane & 15);
    const int side = n >> 5, o = n & 31;
    const float* Wrow = (side ? Wr : Wl) + o * 256 + ((lane >> 4) * 8);
    #pragma unroll
    for (int ks = 0; ks < 8; ++ks) {
      const float4 w0 = *(const float4*)(Wrow + ks * 32);
      const float4 w1 = *(const float4*)(Wrow + ks * 32 + 4);
      unsigned short u[8];
      u[0] = f2bf(w0.x); u[1] = f2bf(w0.y); u[2] = f2bf(w0.z); u[3] = f2bf(w0.w);
      u[4] = f2bf(w1.x); u[5] = f2bf(w1.y); u[6] = f2bf(w1.z); u[7] = f2bf(w1.w);
      wf[ks] = *(bfrag8*)u;
    }
  }

  float mu[16], rs[16];
  #pragma unroll
  for (int i = 0; i < 16; ++i) {
    float s  = xv[i].x + xv[i].y + xv[i].z + xv[i].w;
    float s2 = xv[i].x * xv[i].x + xv[i].y * xv[i].y + xv[i].z * xv[i].z + xv[i].w * xv[i].w;
    #pragma unroll
    for (int off = 32; off >= 1; off >>= 1) {
      s  += __shfl_xor(s, off);
      s2 += __shfl_xor(s2, off);
    }
    mu[i] = s * (1.0f / C);
    rs[i] = rsqrtf(s2 * (1.0f / C) - mu[i] * mu[i] + EPS);
  }

  {
    const float4 wv = *(const float4*)(lnw + lane * 4);
    const float4 bv = *(const float4*)(lnb + lane * 4);
    #pragma unroll
    for (int i = 0; i < 16; ++i) {
      const int r = i * 4 + w;
      float4 v = xv[i];
      unsigned short u[4];
      u[0] = f2bf((v.x - mu[i]) * rs[i] * wv.x + bv.x);
      u[1] = f2bf((v.y - mu[i]) * rs[i] * wv.y + bv.y);
      u[2] = f2bf((v.z - mu[i]) * rs[i] * wv.z + bv.z);
      u[3] = f2bf((v.w - mu[i]) * rs[i] * wv.w + bv.w);
      *(bhalf4*)&xb[r * 512 + ((lane * 8) ^ ((r & 7) << 4))] = *(bhalf4*)u;
    }
  }
  __syncthreads();

  f32x4 acc[4];
  #pragma unroll
  for (int mf = 0; mf < 4; ++mf) acc[mf] = (f32x4)0.f;
  #pragma unroll
  for (int ks = 0; ks < 8; ++ks) {
    #pragma unroll
    for (int mf = 0; mf < 4; ++mf) {
      const int row = mf * 16 + (lane & 15);
      const bfrag8 af = *(const bfrag8*)&xb[row * 512 +
                          ((ks * 64 + ((lane >> 4) << 4)) ^ ((row & 7) << 4))];
      acc[mf] = __builtin_amdgcn_mfma_f32_16x16x32_bf16(af, wf[ks], acc[mf], 0, 0, 0);
    }
  }

  {
    const int n = w * 16 + (lane & 15);
    const int side = n >> 5, o = n & 31;
    const float bias = side ? br[o] : bl[o];
    const float sc = side ? (1.0f / D) : 1.0f;
    unsigned short* dst = side ? rightT : leftT;
    #pragma unroll
    for (int mf = 0; mf < 4; ++mf) {
      const int rbase = mf * 16 + ((lane >> 4) << 2);
      const int ll = rbase >> 3, ddb = rbase & 7;
      unsigned short u[4];
      #pragma unroll
      for (int r = 0; r < 4; ++r) u[r] = f2bf((acc[mf][r] + bias) * sc);
      *(bhalf4*)(dst + ((size_t)(l0 + ll) * 32 + o) * 128 + d0 + ddb) = *(bhalf4*)u;
    }
  }
}

// ---------------- Kernel 2: fused outer-product + output projection --------
// 2048 blocks (XCD-swizzled; tile 4l x 8m = 32 pairs), 512 thr = 8 waves (2x4).
// Phase 1: A1 tail-prefetch (gload_lds) + B1 reg-staged (T14).
// Phase 1.5: b128 Os stores (hi-halves packed; k''-order).
// Phase 2: waves regrouped 4p x 2pair (64 p x 16 pairs each): halves Os LDS
// amplification (512->256 KB/block), doubles wf L2 stream (both unsaturated).
__global__ __launch_bounds__(512, 4)
void fused_mfma(const unsigned short* __restrict__ leftT,
                const unsigned short* __restrict__ rightT,
                const unsigned short* __restrict__ Wbf3,
                const float* __restrict__ bout,
                float* __restrict__ out) {
  __shared__ char smem[65536];   // ph1: A0@0(16K), B@16384(32K), A1@49152(16K); ph2: Os 64K

  const int flat = blockIdx.x;
  const int wg = (flat & 7) * 256 + (flat >> 3);   // bijective (2048 % 8 == 0)
  const int mt = wg & 31, lt = wg >> 5;            // 64 l-tiles x 32 m-tiles
  const int l0 = lt * 4, m0 = mt * 8;

  const char* Aslab = (const char*)(leftT  + (size_t)l0 * 32 * 128);  // 128 rows x 256B
  const char* Bslab = (const char*)(rightT + (size_t)m0 * 32 * 128);  // 256 rows x 256B

  const int tid = threadIdx.x, lane = tid & 63, w = tid >> 6;
  const int wr = w >> 2, wc = w & 3;   // wave tile 64x64 of O (128 rows x 256 cols)

  f32x4 acc[4][4];
  #pragma unroll
  for (int i = 0; i < 4; ++i)
    #pragma unroll
    for (int j = 0; j < 4; ++j) acc[i][j] = (f32x4)0.f;

  auto stageA = [&](int kh, int dst) {
    #pragma unroll
    for (int i = 0; i < 2; ++i) {     // 16KB
      const int lb = (i * 512 + tid) * 16;
      const int row = lb >> 7;
      const int sb = (lb & 127) ^ ((row & 7) << 4);
      __builtin_amdgcn_global_load_lds((const void*)(Aslab + (size_t)row * 256 + kh * 128 + sb),
                                       (void*)&smem[dst + lb], 16, 0, 0);
    }
  };
  auto stageB = [&](int kh) {
    #pragma unroll
    for (int i = 0; i < 4; ++i) {     // 32KB @16384
      const int lb = (i * 512 + tid) * 16;
      const int row = lb >> 7;
      const int sb = (lb & 127) ^ ((row & 7) << 4);
      __builtin_amdgcn_global_load_lds((const void*)(Bslab + (size_t)row * 256 + kh * 128 + sb),
                                       (void*)&smem[16384 + lb], 16, 0, 0);
    }
  };
  auto computeKh = [&](int abase) {
    #pragma unroll
    for (int ks = 0; ks < 2; ++ks) {
      const int kb = ks * 64 + ((lane >> 4) << 4);
      bfrag8 a[4], b[4];
      #pragma unroll
      for (int i = 0; i < 4; ++i) {
        const int row = wr * 64 + i * 16 + (lane & 15);
        a[i] = *(const bfrag8*)&smem[abase + (row << 7) + (kb ^ ((row & 7) << 4))];
      }
      #pragma unroll
      for (int j = 0; j < 4; ++j) {
        const int row = wc * 64 + j * 16 + (lane & 15);
        b[j] = *(const bfrag8*)&smem[16384 + (row << 7) + (kb ^ ((row & 7) << 4))];
      }
      #pragma unroll
      for (int i = 0; i < 4; ++i)
        #pragma unroll
        for (int j = 0; j < 4; ++j)
          acc[i][j] = __builtin_amdgcn_mfma_f32_16x16x32_bf16(a[i], b[j], acc[i][j], 0, 0, 0);
    }
  };

  // ---- Phase 1 ----
  stageA(0, 0);
  stageB(0);
  __syncthreads();
  stageA(1, 49152);              // gload_lds into free tail; overlaps kh0 compute
  u32x4 b1r[4];                  // T14: B1 -> registers, in flight under kh0 compute
  #pragma unroll
  for (int i = 0; i < 4; ++i) {
    const int lb = (i * 512 + tid) * 16;
    const int row = lb >> 7;
    const int sb = (lb & 127) ^ ((row & 7) << 4);
    b1r[i] = *(const u32x4*)(Bslab + (size_t)row * 256 + 128 + sb);
  }
  computeKh(0);
  __syncthreads();               // B0 reads done; A1 + b1r arrived
  #pragma unroll
  for (int i = 0; i < 4; ++i)    // B1 regs -> LDS (same linear layout)
    *(u32x4*)&smem[16384 + (i * 512 + tid) * 16] = b1r[i];
  __syncthreads();               // B1 visible
  computeKh(49152);
  __syncthreads();               // all phase-1 reads done before Os writes

  // ---- Phase 1.5: acc -> Os[pair][k''] via b128 stores (hi-halves packed) ----
  // k'' = q*32 + c2*8 + hi*4 + r; granule byte base = q*64 + c2*16, c2 = lane>>4.
  {
    const int c2_16 = (lane >> 4) << 4;
    #pragma unroll
    for (int ip = 0; ip < 2; ++ip) {          // i = 2*ip (hi=0), 2*ip+1 (hi=1); same ll
      const int ll = wr * 2 + ip;
      #pragma unroll
      for (int j = 0; j < 4; ++j) {
        const int col = wc * 64 + j * 16 + (lane & 15);
        const int mm = col >> 5, q = col & 31;
        const int pair = ll * 8 + mm;         // 0..31
        const int S = (pair & 7) ^ ((q >> 1) & 7);
        const int byte = pair * 2048 + ((q * 64 + c2_16) ^ (S << 4));
        u32x4 u;
        u[0] = (unsigned)f2bf(acc[2 * ip][j][0])     | ((unsigned)f2bf(acc[2 * ip][j][1]) << 16);
        u[1] = (unsigned)f2bf(acc[2 * ip][j][2])     | ((unsigned)f2bf(acc[2 * ip][j][3]) << 16);
        u[2] = (unsigned)f2bf(acc[2 * ip + 1][j][0]) | ((unsigned)f2bf(acc[2 * ip + 1][j][1]) << 16);
        u[3] = (unsigned)f2bf(acc[2 * ip + 1][j][2]) | ((unsigned)f2bf(acc[2 * ip + 1][j][3]) << 16);
        *(u32x4*)&smem[byte] = u;
      }
    }
  }

  // ---- Phase 2 prologue: depth-4 wf prefetch (4 pf/wave) hoisted ABOVE the Os barrier ----
  const int pw = w >> 1;               // p-quarter 0..3 (64 p per wave)
  const unsigned short* wp[4];
  #pragma unroll
  for (int i = 0; i < 4; ++i)
    wp[i] = Wbf3 + (((size_t)(pw * 4 + i) * 32) * 64 + lane) * 8;

  bfrag8 wfs[4][4];
  #pragma unroll
  for (int s = 0; s < 4; ++s)
    #pragma unroll
    for (int i = 0; i < 4; ++i)
      wfs[s][i] = *(const bfrag8*)(wp[i] + s * 512);
  __syncthreads();   // Os ready (wf loads already in flight)

  // ---- Phase 2: OUT[64 p][16 pairs] per wave, K=1024; osf ring depth 3 ----
  f32x4 oacc[4];
  #pragma unroll
  for (int i = 0; i < 4; ++i) oacc[i] = (f32x4)0.f;

  const int pairW = (w & 1) * 16 + (lane & 15);     // wave's pair group
  auto ldos1 = [&](int ks) -> bfrag8 {
    const int S = (pairW & 7) ^ ((ks >> 1) & 7);
    return *(const bfrag8*)&smem[pairW * 2048 +
             ((ks * 64 + ((lane >> 4) << 4)) ^ (S << 4))];
  };

  bfrag8 osf[4];
  osf[0] = ldos1(0);
  osf[1] = ldos1(1);
  osf[2] = ldos1(2);

  #pragma unroll
  for (int ks = 0; ks < 32; ++ks) {
    if (ks + 3 < 32) osf[(ks + 3) & 3] = ldos1(ks + 3);   // compile-time slot
    __builtin_amdgcn_s_setprio(1);
    oacc[0] = __builtin_amdgcn_mfma_f32_16x16x32_bf16(wfs[ks & 3][0], osf[ks & 3], oacc[0], 0, 0, 0);
    oacc[1] = __builtin_amdgcn_mfma_f32_16x16x32_bf16(wfs[ks & 3][1], osf[ks & 3], oacc[1], 0, 0, 0);
    oacc[2] = __builtin_amdgcn_mfma_f32_16x16x32_bf16(wfs[ks & 3][2], osf[ks & 3], oacc[2], 0, 0, 0);
    oacc[3] = __builtin_amdgcn_mfma_f32_16x16x32_bf16(wfs[ks & 3][3], osf[ks & 3], oacc[3], 0, 0, 0);
    __builtin_amdgcn_s_setprio(0);
    if (ks + 4 < 32) {                                    // refill consumed wf slot
      #pragma unroll
      for (int i = 0; i < 4; ++i)
        wfs[ks & 3][i] = *(const bfrag8*)(wp[i] + (ks + 4) * 512);
    }
  }

  // ---- epilogue: row = p (regs), col = pair ----
  {
    const int ll = pairW >> 3, mm = pairW & 7;
    const size_t rowbase = ((size_t)(l0 + ll) * L + (m0 + mm)) * PC;
    #pragma unroll
    for (int i = 0; i < 4; ++i) {
      const int p0 = pw * 64 + i * 16 + ((lane >> 4) << 2);
      const float4 bb = *(const float4*)&bout[p0];
      float4 v;
      v.x = oacc[i][0] + bb.x;
      v.y = oacc[i][1] + bb.y;
      v.z = oacc[i][2] + bb.z;
      v.w = oacc[i][3] + bb.w;
      *(float4*)&out[rowbase + p0] = v;
    }
  }
}

extern "C" void kernel_launch(void* const* d_in, const int* in_sizes, int n_in,
                              void* d_out, int out_size, void* d_ws, size_t ws_size,
                              hipStream_t stream) {
  const float* msa  = (const float*)d_in[0];
  const float* ln_w = (const float*)d_in[1];
  const float* ln_b = (const float*)d_in[2];
  const float* Wl   = (const float*)d_in[3];
  const float* bl   = (const float*)d_in[4];
  const float* Wr   = (const float*)d_in[5];
  const float* br   = (const float*)d_in[6];
  const float* Wout = (const float*)d_in[7];
  const float* bout = (const float*)d_in[8];
  float* out = (float*)d_out;

  unsigned short* leftT  = (unsigned short*)d_ws;                 // [L*32][128] bf16 = 2 MB
  unsigned short* rightT = leftT + (size_t)L * 32 * 128;          // 2 MB
  unsigned short* Wbf3   = rightT + (size_t)L * 32 * 128;         // 512 KB (frag-packed)

  prep_ln<<<dim3(576), 256, 0, stream>>>(msa, ln_w, ln_b, Wl, Wr, Wout, bl, br,
                                         Wbf3, leftT, rightT);
  fused_mfma<<<dim3(2048), 512, 0, stream>>>(leftT, rightT, Wbf3, bout, out);
}

// Round 18
// 81.732 us; speedup vs baseline: 1.2637x; 1.2637x over previous
//
#include <hip/hip_runtime.h>

#define EPS 1e-5f

static constexpr int D  = 128;
static constexpr int L  = 256;
static constexpr int C  = 256;
static constexpr int OC = 32;
static constexpr int PC = 256;

typedef __attribute__((ext_vector_type(8))) short bfrag8;   // 8 bf16 (4 VGPR)
typedef __attribute__((ext_vector_type(4))) short bhalf4;   // 4 bf16 (8B)
typedef __attribute__((ext_vector_type(4))) float f32x4;
typedef __attribute__((ext_vector_type(4))) unsigned int u32x4;

__device__ inline unsigned short f2bf(float f) {
  union { float f; unsigned u; } v; v.f = f;
  unsigned r = v.u + 0x7FFF + ((v.u >> 16) & 1);   // RNE
  return (unsigned short)(r >> 16);
}

// ---------------- Kernel 1: prep (blocks 0..63) + LayerNorm/projection (blocks 64..575) ----
// prep part: Wbf3 = Wout bf16 in MFMA A-frag order (M-side = p), k''-ordered:
//   k'' = q*32 + c2*8 + hi*4 + r  <->  cc = hi*16 + c2*4 + r; orig = cc*32 + q.
//   elem ((pf*32+ks)*64+lane)*8+jj = Wout[p = pf*16+(lane&15)][orig(k'')],
//   k'' = ks*32 + (lane>>4)*8 + jj.
// ln part: block = 8 d x 8 l rows; weight frags built inline from Wl/Wr (L2-hot).
__global__ __launch_bounds__(256, 4)
void prep_ln(const float* __restrict__ msa,
             const float* __restrict__ lnw, const float* __restrict__ lnb,
             const float* __restrict__ Wl, const float* __restrict__ Wr,
             const float* __restrict__ Wout,
             const float* __restrict__ bl, const float* __restrict__ br,
             unsigned short* __restrict__ Wbf3,
             unsigned short* __restrict__ leftT, unsigned short* __restrict__ rightT) {
  const int t = threadIdx.x;
  const int b = blockIdx.x;

  if (b < 64) {   // ---- Wbf3 frag-pack: 64 blocks x 256 thr x 16 elems ----
    #pragma unroll
    for (int j2 = 0; j2 < 4; ++j2) {
      const int e0 = (b * 256 + t) * 16 + j2 * 4;
      const int lane = (e0 >> 3) & 63, ks = (e0 >> 9) & 31, pf = e0 >> 14;
      const int p = pf * 16 + (lane & 15);
      unsigned short v[4];
      #pragma unroll
      for (int j = 0; j < 4; ++j) {
        const int kp = ks * 32 + ((lane >> 4) * 8) + ((e0 + j) & 7);   // k''
        const int q = kp >> 5, t5 = kp & 31;
        const int cc = ((t5 >> 2) & 1) * 16 + (t5 >> 3) * 4 + (t5 & 3);
        v[j] = f2bf(Wout[p * 1024 + cc * 32 + q]);
      }
      *(bhalf4*)(Wbf3 + e0) = *(bhalf4*)v;
    }
    return;
  }

  // ---- ln_proj part ----
  __shared__ char xb[32768];   // [64 r][256 c] bf16, swizzled ^((r&7)<<4)

  const int bb = b - 64;
  const int lane = t & 63, w = t >> 6;
  const int d0 = (bb & 15) * 8, l0 = (bb >> 4) * 8;

  float4 xv[16];
  #pragma unroll
  for (int i = 0; i < 16; ++i) {
    const int r = i * 4 + w, dd = r & 7, ll = r >> 3;
    xv[i] = *(const float4*)(msa + ((size_t)(d0 + dd) * 256 + (l0 + ll)) * 256 + lane * 4);
  }

  // build weight frags inline: n = w*16+(lane&15)
  bfrag8 wf[8];
  {
    const int n = w * 16 + (lane & 15);
    const int side = n >> 5, o = n & 31;
    const float* Wrow = (side ? Wr : Wl) + o * 256 + ((lane >> 4) * 8);
    #pragma unroll
    for (int ks = 0; ks < 8; ++ks) {
      const float4 w0 = *(const float4*)(Wrow + ks * 32);
      const float4 w1 = *(const float4*)(Wrow + ks * 32 + 4);
      unsigned short u[8];
      u[0] = f2bf(w0.x); u[1] = f2bf(w0.y); u[2] = f2bf(w0.z); u[3] = f2bf(w0.w);
      u[4] = f2bf(w1.x); u[5] = f2bf(w1.y); u[6] = f2bf(w1.z); u[7] = f2bf(w1.w);
      wf[ks] = *(bfrag8*)u;
    }
  }

  float mu[16], rs[16];
  #pragma unroll
  for (int i = 0; i < 16; ++i) {
    float s  = xv[i].x + xv[i].y + xv[i].z + xv[i].w;
    float s2 = xv[i].x * xv[i].x + xv[i].y * xv[i].y + xv[i].z * xv[i].z + xv[i].w * xv[i].w;
    #pragma unroll
    for (int off = 32; off >= 1; off >>= 1) {
      s  += __shfl_xor(s, off);
      s2 += __shfl_xor(s2, off);
    }
    mu[i] = s * (1.0f / C);
    rs[i] = rsqrtf(s2 * (1.0f / C) - mu[i] * mu[i] + EPS);
  }

  {
    const float4 wv = *(const float4*)(lnw + lane * 4);
    const float4 bv = *(const float4*)(lnb + lane * 4);
    #pragma unroll
    for (int i = 0; i < 16; ++i) {
      const int r = i * 4 + w;
      float4 v = xv[i];
      unsigned short u[4];
      u[0] = f2bf((v.x - mu[i]) * rs[i] * wv.x + bv.x);
      u[1] = f2bf((v.y - mu[i]) * rs[i] * wv.y + bv.y);
      u[2] = f2bf((v.z - mu[i]) * rs[i] * wv.z + bv.z);
      u[3] = f2bf((v.w - mu[i]) * rs[i] * wv.w + bv.w);
      *(bhalf4*)&xb[r * 512 + ((lane * 8) ^ ((r & 7) << 4))] = *(bhalf4*)u;
    }
  }
  __syncthreads();

  f32x4 acc[4];
  #pragma unroll
  for (int mf = 0; mf < 4; ++mf) acc[mf] = (f32x4)0.f;
  #pragma unroll
  for (int ks = 0; ks < 8; ++ks) {
    #pragma unroll
    for (int mf = 0; mf < 4; ++mf) {
      const int row = mf * 16 + (lane & 15);
      const bfrag8 af = *(const bfrag8*)&xb[row * 512 +
                          ((ks * 64 + ((lane >> 4) << 4)) ^ ((row & 7) << 4))];
      acc[mf] = __builtin_amdgcn_mfma_f32_16x16x32_bf16(af, wf[ks], acc[mf], 0, 0, 0);
    }
  }

  {
    const int n = w * 16 + (lane & 15);
    const int side = n >> 5, o = n & 31;
    const float bias = side ? br[o] : bl[o];
    const float sc = side ? (1.0f / D) : 1.0f;
    unsigned short* dst = side ? rightT : leftT;
    #pragma unroll
    for (int mf = 0; mf < 4; ++mf) {
      const int rbase = mf * 16 + ((lane >> 4) << 2);
      const int ll = rbase >> 3, ddb = rbase & 7;
      unsigned short u[4];
      #pragma unroll
      for (int r = 0; r < 4; ++r) u[r] = f2bf((acc[mf][r] + bias) * sc);
      *(bhalf4*)(dst + ((size_t)(l0 + ll) * 32 + o) * 128 + d0 + ddb) = *(bhalf4*)u;
    }
  }
}

// ---------------- Kernel 2: fused outer-product + output projection --------
// 2048 blocks (XCD-swizzled; tile 4l x 8m = 32 pairs), 512 thr = 8 waves (2x4).
// Phase 1: A1 tail-prefetch (gload_lds) + B1 reg-staged (T14).
// Phase 1.5: b128 Os stores (hi-halves packed; k''-order).
// Phase 2: osf ring depth 3 + wfs ring depth 4 + setprio (2pf x 2pair grouping —
// measured optimum of the phase-2 traffic balance, r14/r16 vs r17).
__global__ __launch_bounds__(512, 4)
void fused_mfma(const unsigned short* __restrict__ leftT,
                const unsigned short* __restrict__ rightT,
                const unsigned short* __restrict__ Wbf3,
                const float* __restrict__ bout,
                float* __restrict__ out) {
  __shared__ char smem[65536];   // ph1: A0@0(16K), B@16384(32K), A1@49152(16K); ph2: Os 64K

  const int flat = blockIdx.x;
  const int wg = (flat & 7) * 256 + (flat >> 3);   // bijective (2048 % 8 == 0)
  const int mt = wg & 31, lt = wg >> 5;            // 64 l-tiles x 32 m-tiles
  const int l0 = lt * 4, m0 = mt * 8;

  const char* Aslab = (const char*)(leftT  + (size_t)l0 * 32 * 128);  // 128 rows x 256B
  const char* Bslab = (const char*)(rightT + (size_t)m0 * 32 * 128);  // 256 rows x 256B

  const int tid = threadIdx.x, lane = tid & 63, w = tid >> 6;
  const int wr = w >> 2, wc = w & 3;   // wave tile 64x64 of O (128 rows x 256 cols)

  f32x4 acc[4][4];
  #pragma unroll
  for (int i = 0; i < 4; ++i)
    #pragma unroll
    for (int j = 0; j < 4; ++j) acc[i][j] = (f32x4)0.f;

  auto stageA = [&](int kh, int dst) {
    #pragma unroll
    for (int i = 0; i < 2; ++i) {     // 16KB
      const int lb = (i * 512 + tid) * 16;
      const int row = lb >> 7;
      const int sb = (lb & 127) ^ ((row & 7) << 4);
      __builtin_amdgcn_global_load_lds((const void*)(Aslab + (size_t)row * 256 + kh * 128 + sb),
                                       (void*)&smem[dst + lb], 16, 0, 0);
    }
  };
  auto stageB = [&](int kh) {
    #pragma unroll
    for (int i = 0; i < 4; ++i) {     // 32KB @16384
      const int lb = (i * 512 + tid) * 16;
      const int row = lb >> 7;
      const int sb = (lb & 127) ^ ((row & 7) << 4);
      __builtin_amdgcn_global_load_lds((const void*)(Bslab + (size_t)row * 256 + kh * 128 + sb),
                                       (void*)&smem[16384 + lb], 16, 0, 0);
    }
  };
  auto computeKh = [&](int abase) {
    #pragma unroll
    for (int ks = 0; ks < 2; ++ks) {
      const int kb = ks * 64 + ((lane >> 4) << 4);
      bfrag8 a[4], b[4];
      #pragma unroll
      for (int i = 0; i < 4; ++i) {
        const int row = wr * 64 + i * 16 + (lane & 15);
        a[i] = *(const bfrag8*)&smem[abase + (row << 7) + (kb ^ ((row & 7) << 4))];
      }
      #pragma unroll
      for (int j = 0; j < 4; ++j) {
        const int row = wc * 64 + j * 16 + (lane & 15);
        b[j] = *(const bfrag8*)&smem[16384 + (row << 7) + (kb ^ ((row & 7) << 4))];
      }
      #pragma unroll
      for (int i = 0; i < 4; ++i)
        #pragma unroll
        for (int j = 0; j < 4; ++j)
          acc[i][j] = __builtin_amdgcn_mfma_f32_16x16x32_bf16(a[i], b[j], acc[i][j], 0, 0, 0);
    }
  };

  // ---- Phase 1 ----
  stageA(0, 0);
  stageB(0);
  __syncthreads();
  stageA(1, 49152);              // gload_lds into free tail; overlaps kh0 compute
  u32x4 b1r[4];                  // T14: B1 -> registers, in flight under kh0 compute
  #pragma unroll
  for (int i = 0; i < 4; ++i) {
    const int lb = (i * 512 + tid) * 16;
    const int row = lb >> 7;
    const int sb = (lb & 127) ^ ((row & 7) << 4);
    b1r[i] = *(const u32x4*)(Bslab + (size_t)row * 256 + 128 + sb);
  }
  computeKh(0);
  __syncthreads();               // B0 reads done; A1 + b1r arrived
  #pragma unroll
  for (int i = 0; i < 4; ++i)    // B1 regs -> LDS (same linear layout)
    *(u32x4*)&smem[16384 + (i * 512 + tid) * 16] = b1r[i];
  __syncthreads();               // B1 visible
  computeKh(49152);
  __syncthreads();               // all phase-1 reads done before Os writes

  // ---- Phase 1.5: acc -> Os[pair][k''] via b128 stores (hi-halves packed) ----
  // k'' = q*32 + c2*8 + hi*4 + r; granule byte base = q*64 + c2*16, c2 = lane>>4.
  {
    const int c2_16 = (lane >> 4) << 4;
    #pragma unroll
    for (int ip = 0; ip < 2; ++ip) {          // i = 2*ip (hi=0), 2*ip+1 (hi=1); same ll
      const int ll = wr * 2 + ip;
      #pragma unroll
      for (int j = 0; j < 4; ++j) {
        const int col = wc * 64 + j * 16 + (lane & 15);
        const int mm = col >> 5, q = col & 31;
        const int pair = ll * 8 + mm;         // 0..31
        const int S = (pair & 7) ^ ((q >> 1) & 7);
        const int byte = pair * 2048 + ((q * 64 + c2_16) ^ (S << 4));
        u32x4 u;
        u[0] = (unsigned)f2bf(acc[2 * ip][j][0])     | ((unsigned)f2bf(acc[2 * ip][j][1]) << 16);
        u[1] = (unsigned)f2bf(acc[2 * ip][j][2])     | ((unsigned)f2bf(acc[2 * ip][j][3]) << 16);
        u[2] = (unsigned)f2bf(acc[2 * ip + 1][j][0]) | ((unsigned)f2bf(acc[2 * ip + 1][j][1]) << 16);
        u[3] = (unsigned)f2bf(acc[2 * ip + 1][j][2]) | ((unsigned)f2bf(acc[2 * ip + 1][j][3]) << 16);
        *(u32x4*)&smem[byte] = u;
      }
    }
  }

  // ---- Phase 2 prologue: depth-4 wf prefetch hoisted ABOVE the Os barrier ----
  const unsigned short* wp0 = Wbf3 + (((size_t)(w * 2)     * 32) * 64 + lane) * 8;
  const unsigned short* wp1 = Wbf3 + (((size_t)(w * 2 + 1) * 32) * 64 + lane) * 8;

  bfrag8 wfs[4][2];
  #pragma unroll
  for (int s = 0; s < 4; ++s) {
    wfs[s][0] = *(const bfrag8*)(wp0 + s * 512);
    wfs[s][1] = *(const bfrag8*)(wp1 + s * 512);
  }
  __syncthreads();   // Os ready (wf loads already in flight)

  // ---- Phase 2: OUT[256 p][32 pairs], K=1024; osf ring depth 3 + wfs ring ----
  f32x4 oacc[2][2];
  #pragma unroll
  for (int u = 0; u < 2; ++u)
    #pragma unroll
    for (int pj = 0; pj < 2; ++pj) oacc[u][pj] = (f32x4)0.f;

  auto ldos = [&](int ks, bfrag8* o) {
    #pragma unroll
    for (int pj = 0; pj < 2; ++pj) {
      const int pair = pj * 16 + (lane & 15);
      const int S = (pair & 7) ^ ((ks >> 1) & 7);
      o[pj] = *(const bfrag8*)&smem[pair * 2048 + ((ks * 64 + ((lane >> 4) << 4)) ^ (S << 4))];
    }
  };

  bfrag8 osf[4][2];
  ldos(0, osf[0]);
  ldos(1, osf[1]);
  ldos(2, osf[2]);

  #pragma unroll
  for (int ks = 0; ks < 32; ++ks) {
    if (ks + 3 < 32) ldos(ks + 3, osf[(ks + 3) & 3]);   // compile-time slot
    __builtin_amdgcn_s_setprio(1);
    oacc[0][0] = __builtin_amdgcn_mfma_f32_16x16x32_bf16(wfs[ks & 3][0], osf[ks & 3][0], oacc[0][0], 0, 0, 0);
    oacc[0][1] = __builtin_amdgcn_mfma_f32_16x16x32_bf16(wfs[ks & 3][0], osf[ks & 3][1], oacc[0][1], 0, 0, 0);
    oacc[1][0] = __builtin_amdgcn_mfma_f32_16x16x32_bf16(wfs[ks & 3][1], osf[ks & 3][0], oacc[1][0], 0, 0, 0);
    oacc[1][1] = __builtin_amdgcn_mfma_f32_16x16x32_bf16(wfs[ks & 3][1], osf[ks & 3][1], oacc[1][1], 0, 0, 0);
    __builtin_amdgcn_s_setprio(0);
    if (ks + 4 < 32) {                                   // refill consumed wf slot
      wfs[ks & 3][0] = *(const bfrag8*)(wp0 + (ks + 4) * 512);
      wfs[ks & 3][1] = *(const bfrag8*)(wp1 + (ks + 4) * 512);
    }
  }

  // ---- epilogue: row = p (regs), col = pair ----
  {
    #pragma unroll
    for (int u = 0; u < 2; ++u) {
      const int p0 = (w * 2 + u) * 16 + ((lane >> 4) << 2);
      const float4 bb = *(const float4*)&bout[p0];
      #pragma unroll
      for (int pj = 0; pj < 2; ++pj) {
        const int pair = pj * 16 + (lane & 15);
        const int ll = pair >> 3, mm = pair & 7;
        float4 v;
        v.x = oacc[u][pj][0] + bb.x;
        v.y = oacc[u][pj][1] + bb.y;
        v.z = oacc[u][pj][2] + bb.z;
        v.w = oacc[u][pj][3] + bb.w;
        *(float4*)&out[((size_t)(l0 + ll) * L + (m0 + mm)) * PC + p0] = v;
      }
    }
  }
}

extern "C" void kernel_launch(void* const* d_in, const int* in_sizes, int n_in,
                              void* d_out, int out_size, void* d_ws, size_t ws_size,
                              hipStream_t stream) {
  const float* msa  = (const float*)d_in[0];
  const float* ln_w = (const float*)d_in[1];
  const float* ln_b = (const float*)d_in[2];
  const float* Wl   = (const float*)d_in[3];
  const float* bl   = (const float*)d_in[4];
  const float* Wr   = (const float*)d_in[5];
  const float* br   = (const float*)d_in[6];
  const float* Wout = (const float*)d_in[7];
  const float* bout = (const float*)d_in[8];
  float* out = (float*)d_out;

  unsigned short* leftT  = (unsigned short*)d_ws;                 // [L*32][128] bf16 = 2 MB
  unsigned short* rightT = leftT + (size_t)L * 32 * 128;          // 2 MB
  unsigned short* Wbf3   = rightT + (size_t)L * 32 * 128;         // 512 KB (frag-packed)

  prep_ln<<<dim3(576), 256, 0, stream>>>(msa, ln_w, ln_b, Wl, Wr, Wout, bl, br,
                                         Wbf3, leftT, rightT);
  fused_mfma<<<dim3(2048), 512, 0, stream>>>(leftT, rightT, Wbf3, bout, out);
}